// Round 4
// baseline (413.814 us; speedup 1.0000x reference)
//
#include <hip/hip_runtime.h>

#define D 256

typedef short short8 __attribute__((ext_vector_type(8)));
typedef float f32x4 __attribute__((ext_vector_type(4)));

// bf16 helpers (RNE)
__device__ __forceinline__ unsigned short f2bf(float f) {
    unsigned int u = __float_as_uint(f);
    unsigned int r = (u + 0x7FFFu + ((u >> 16) & 1u)) >> 16;
    return (unsigned short)r;
}
__device__ __forceinline__ float bf2f(unsigned short h) {
    return __uint_as_float(((unsigned int)h) << 16);
}

// ---------------- small utils ----------------

__global__ void zero_int(int* __restrict__ p, int n) {
    int i = blockIdx.x * blockDim.x + threadIdx.x;
    if (i < n) p[i] = 0;
}

// ---------------- CSR build ----------------

__global__ void degree_kernel(const int* __restrict__ dst, int* __restrict__ deg, int E) {
    int e = blockIdx.x * blockDim.x + threadIdx.x;
    if (e < E) atomicAdd(&deg[dst[e]], 1);
}

__global__ __launch_bounds__(1024) void scan_kernel(const int* __restrict__ deg,
                                                    int* __restrict__ offsets,
                                                    int* __restrict__ cursor, int n) {
    const int CHUNK = 16;
    __shared__ int s[1024];
    int t = threadIdx.x;
    int base_idx = t * CHUNK;
    int vals[CHUNK];
    int local = 0;
#pragma unroll
    for (int i = 0; i < CHUNK; ++i) {
        int idx = base_idx + i;
        int v = (idx < n) ? deg[idx] : 0;
        vals[i] = v;
        local += v;
    }
    s[t] = local;
    __syncthreads();
    for (int off = 1; off < 1024; off <<= 1) {
        int v = (t >= off) ? s[t - off] : 0;
        __syncthreads();
        s[t] += v;
        __syncthreads();
    }
    int run = s[t] - local;
#pragma unroll
    for (int i = 0; i < CHUNK; ++i) {
        int idx = base_idx + i;
        if (idx < n) {
            offsets[idx] = run;
            cursor[idx]  = run;
            run += vals[i];
        }
    }
    if (t == 1023) offsets[n] = s[1023];
}

__global__ void bucket_kernel(const int* __restrict__ src, const int* __restrict__ dst,
                              int* __restrict__ cursor, int* __restrict__ csr, int E) {
    int e = blockIdx.x * blockDim.x + threadIdx.x;
    if (e < E) {
        int d = dst[e];
        int pos = atomicAdd(&cursor[d], 1);
        csr[pos] = src[e];
    }
}

// ---------------- conversions ----------------
// Ah/Al layout: [M rows][512 cols] bf16; cols 0..255 = agg (written later by agg_kernel),
// cols 256..511 = x. Bh/Bl: [256 rows][512 cols]; cols 0..255 = W_l row, 256..511 = W_r row.

__global__ void cvt_x_kernel(const float* __restrict__ x,
                             unsigned short* __restrict__ Ah,
                             unsigned short* __restrict__ Al, int total4) {
    int i = blockIdx.x * blockDim.x + threadIdx.x;
    if (i >= total4) return;
    int m = i >> 6;
    int c = (i & 63) << 2;
    float4 v = *(const float4*)&x[(long)m * 256 + c];
    ushort4 h, l;
    h.x = f2bf(v.x); l.x = f2bf(v.x - bf2f(h.x));
    h.y = f2bf(v.y); l.y = f2bf(v.y - bf2f(h.y));
    h.z = f2bf(v.z); l.z = f2bf(v.z - bf2f(h.z));
    h.w = f2bf(v.w); l.w = f2bf(v.w - bf2f(h.w));
    *(ushort4*)&Ah[(long)m * 512 + 256 + c] = h;
    *(ushort4*)&Al[(long)m * 512 + 256 + c] = l;
}

__global__ void cvt_w_kernel(const float* __restrict__ W_l, const float* __restrict__ W_r,
                             unsigned short* __restrict__ Bh,
                             unsigned short* __restrict__ Bl) {
    int i = blockIdx.x * blockDim.x + threadIdx.x;
    if (i >= 32768) return;
    int n = i >> 7;
    int k4 = (i & 127) << 2;
    float4 v = (k4 < 256) ? *(const float4*)&W_l[(long)n * 256 + k4]
                          : *(const float4*)&W_r[(long)n * 256 + (k4 - 256)];
    ushort4 h, l;
    h.x = f2bf(v.x); l.x = f2bf(v.x - bf2f(h.x));
    h.y = f2bf(v.y); l.y = f2bf(v.y - bf2f(h.y));
    h.z = f2bf(v.z); l.z = f2bf(v.z - bf2f(h.z));
    h.w = f2bf(v.w); l.w = f2bf(v.w - bf2f(h.w));
    *(ushort4*)&Bh[(long)n * 512 + k4] = h;
    *(ushort4*)&Bl[(long)n * 512 + k4] = l;
}

// ---------------- aggregation: one wave per node, bf16-hi gather ----------------
// Reads the x-half of Ah (cols 256..511); writes agg hi/lo into cols 0..255.

__global__ __launch_bounds__(256) void agg_kernel(const int* __restrict__ csr,
                                                  const int* __restrict__ offsets,
                                                  unsigned short* __restrict__ Ah,
                                                  unsigned short* __restrict__ Al, int M) {
    int node = (blockIdx.x * 256 + threadIdx.x) >> 6;
    int lane = threadIdx.x & 63;
    if (node >= M) return;
    int start = offsets[node];
    int end   = offsets[node + 1];
    const unsigned short* xb = Ah + 256 + lane * 4;  // row stride 512
    float4 acc = {0.f, 0.f, 0.f, 0.f};
    int e = start;
    for (; e + 4 <= end; e += 4) {
        int s0 = csr[e + 0], s1 = csr[e + 1], s2 = csr[e + 2], s3 = csr[e + 3];
        ushort4 v0 = *(const ushort4*)(xb + (long)s0 * 512);
        ushort4 v1 = *(const ushort4*)(xb + (long)s1 * 512);
        ushort4 v2 = *(const ushort4*)(xb + (long)s2 * 512);
        ushort4 v3 = *(const ushort4*)(xb + (long)s3 * 512);
        acc.x += bf2f(v0.x) + bf2f(v1.x) + bf2f(v2.x) + bf2f(v3.x);
        acc.y += bf2f(v0.y) + bf2f(v1.y) + bf2f(v2.y) + bf2f(v3.y);
        acc.z += bf2f(v0.z) + bf2f(v1.z) + bf2f(v2.z) + bf2f(v3.z);
        acc.w += bf2f(v0.w) + bf2f(v1.w) + bf2f(v2.w) + bf2f(v3.w);
    }
    for (; e < end; ++e) {
        int s = csr[e];
        ushort4 v = *(const ushort4*)(xb + (long)s * 512);
        acc.x += bf2f(v.x); acc.y += bf2f(v.y); acc.z += bf2f(v.z); acc.w += bf2f(v.w);
    }
    int cnt = end - start;
    float sc = 1.0f / (float)(cnt > 0 ? cnt : 1);
    acc.x *= sc; acc.y *= sc; acc.z *= sc; acc.w *= sc;
    ushort4 h, l;
    h.x = f2bf(acc.x); l.x = f2bf(acc.x - bf2f(h.x));
    h.y = f2bf(acc.y); l.y = f2bf(acc.y - bf2f(h.y));
    h.z = f2bf(acc.z); l.z = f2bf(acc.z - bf2f(h.z));
    h.w = f2bf(acc.w); l.w = f2bf(acc.w - bf2f(h.w));
    *(ushort4*)&Ah[(long)node * 512 + lane * 4] = h;
    *(ushort4*)&Al[(long)node * 512 + lane * 4] = l;
}

// ---------------- layer 1: split-bf16 MFMA GEMM ----------------
// h1 = relu(A @ B^T + b_l), A=[agg|x] (M x 512), B=[W_l|W_r] (256 x 512).
// Block = 4 waves; wave owns 16 rows x 64 cols (4 MFMA 16x16x32 col-tiles).
// Split: a = ah + al, b = bh + bl; acc += ah*bh + ah*bl + al*bh (al*bl dropped, ~2^-18).

__global__ __launch_bounds__(256) void gemm1_mfma(const unsigned short* __restrict__ Ah,
                                                  const unsigned short* __restrict__ Al,
                                                  const unsigned short* __restrict__ Bh,
                                                  const unsigned short* __restrict__ Bl,
                                                  const float* __restrict__ bias,
                                                  float* __restrict__ C, int M) {
    const int tid  = threadIdx.x;
    const int wave = tid >> 6;
    const int lane = tid & 63;
    const int l16  = lane & 15;
    const int quad = lane >> 4;
    const int m_base = blockIdx.x * 64 + wave * 16;
    const int n_base = blockIdx.y * 64;

    int rowA = m_base + l16;
    if (rowA > M - 1) rowA = M - 1;  // clamp; stores guarded below
    const unsigned short* pAh = Ah + (long)rowA * 512 + quad * 8;
    const unsigned short* pAl = Al + (long)rowA * 512 + quad * 8;

    f32x4 acc[4] = {};

#pragma unroll 2
    for (int kk = 0; kk < 512; kk += 32) {
        short8 ah = *(const short8*)(pAh + kk);
        short8 al = *(const short8*)(pAl + kk);
#pragma unroll
        for (int t = 0; t < 4; ++t) {
            long off = (long)(n_base + t * 16 + l16) * 512 + quad * 8 + kk;
            short8 bh = *(const short8*)(Bh + off);
            short8 bl = *(const short8*)(Bl + off);
            acc[t] = __builtin_amdgcn_mfma_f32_16x16x32_bf16(ah, bh, acc[t], 0, 0, 0);
            acc[t] = __builtin_amdgcn_mfma_f32_16x16x32_bf16(ah, bl, acc[t], 0, 0, 0);
            acc[t] = __builtin_amdgcn_mfma_f32_16x16x32_bf16(al, bh, acc[t], 0, 0, 0);
        }
    }

    // C/D layout: col = lane&15, row = quad*4 + reg
#pragma unroll
    for (int t = 0; t < 4; ++t) {
        int n = n_base + t * 16 + l16;
        float bv = bias[n];
#pragma unroll
        for (int r = 0; r < 4; ++r) {
            int m = m_base + quad * 4 + r;
            if (m < M) C[(long)m * 256 + n] = fmaxf(acc[t][r] + bv, 0.f);
        }
    }
}

// ---------------- fused layers 2..5: one block owns 8 rows ----------------

__global__ __launch_bounds__(256) void mlp_fused(const float* __restrict__ h1,
                                                 const float* __restrict__ Wa,
                                                 const float* __restrict__ ba,
                                                 const float* __restrict__ W1,
                                                 const float* __restrict__ b1,
                                                 const float* __restrict__ W2,
                                                 const float* __restrict__ b2,
                                                 const float* __restrict__ W3,
                                                 const float* __restrict__ b3,
                                                 float* __restrict__ out, int M) {
    __shared__ float sA[8][260];
    __shared__ float sH2[8][132];
    __shared__ float sH3[8][68];
    __shared__ float sH4[8][36];

    const int tid = threadIdx.x;
    const int r0 = blockIdx.x * 8;
    const int row = tid >> 5;   // 0..7
    const int l   = tid & 31;

    // stage h1 tile: 8x256 = 512 float4
    for (int i = tid; i < 512; i += 256) {
        int rr = i >> 6;
        int c = (i & 63) << 2;
        float4 v = {0.f, 0.f, 0.f, 0.f};
        if (r0 + rr < M) v = *(const float4*)&h1[(long)(r0 + rr) * 256 + c];
        *(float4*)&sA[rr][c] = v;
    }
    __syncthreads();

    // layer 2: cols l*4..+3, K=256
    {
        float4 bv = *(const float4*)&ba[l * 4];
        float acc[4] = {bv.x, bv.y, bv.z, bv.w};
        for (int k = 0; k < 256; k += 4) {
            float4 a = *(const float4*)&sA[row][k];
            float4 w0 = *(const float4*)&Wa[(long)(l * 4 + 0) * 256 + k];
            float4 w1 = *(const float4*)&Wa[(long)(l * 4 + 1) * 256 + k];
            float4 w2 = *(const float4*)&Wa[(long)(l * 4 + 2) * 256 + k];
            float4 w3 = *(const float4*)&Wa[(long)(l * 4 + 3) * 256 + k];
            acc[0] = fmaf(a.x, w0.x, fmaf(a.y, w0.y, fmaf(a.z, w0.z, fmaf(a.w, w0.w, acc[0]))));
            acc[1] = fmaf(a.x, w1.x, fmaf(a.y, w1.y, fmaf(a.z, w1.z, fmaf(a.w, w1.w, acc[1]))));
            acc[2] = fmaf(a.x, w2.x, fmaf(a.y, w2.y, fmaf(a.z, w2.z, fmaf(a.w, w2.w, acc[2]))));
            acc[3] = fmaf(a.x, w3.x, fmaf(a.y, w3.y, fmaf(a.z, w3.z, fmaf(a.w, w3.w, acc[3]))));
        }
        float4 o;
        o.x = fmaxf(acc[0], 0.f);
        o.y = fmaxf(acc[1], 0.f);
        o.z = fmaxf(acc[2], 0.f);
        o.w = fmaxf(acc[3], 0.f);
        *(float4*)&sH2[row][l * 4] = o;
    }
    __syncthreads();

    // layer 3: cols l*2..+1, K=128
    {
        float acc0 = b1[l * 2], acc1 = b1[l * 2 + 1];
        for (int k = 0; k < 128; k += 4) {
            float4 a = *(const float4*)&sH2[row][k];
            float4 w0 = *(const float4*)&W1[(long)(l * 2 + 0) * 128 + k];
            float4 w1 = *(const float4*)&W1[(long)(l * 2 + 1) * 128 + k];
            acc0 = fmaf(a.x, w0.x, fmaf(a.y, w0.y, fmaf(a.z, w0.z, fmaf(a.w, w0.w, acc0))));
            acc1 = fmaf(a.x, w1.x, fmaf(a.y, w1.y, fmaf(a.z, w1.z, fmaf(a.w, w1.w, acc1))));
        }
        float2 o;
        o.x = fmaxf(acc0, 0.f);
        o.y = fmaxf(acc1, 0.f);
        *(float2*)&sH3[row][l * 2] = o;
    }
    __syncthreads();

    // layer 4: col l, K=64
    {
        float acc = b2[l];
        for (int k = 0; k < 64; k += 4) {
            float4 a = *(const float4*)&sH3[row][k];
            float4 w = *(const float4*)&W2[(long)l * 64 + k];
            acc = fmaf(a.x, w.x, fmaf(a.y, w.y, fmaf(a.z, w.z, fmaf(a.w, w.w, acc))));
        }
        sH4[row][l] = fmaxf(acc, 0.f);
    }
    __syncthreads();

    // layer 5: 8 rows x 3 cols = 24 threads
    if (tid < 24) {
        int rr = tid / 3;
        int col = tid - rr * 3;
        float acc = b3[col];
        for (int k = 0; k < 32; k += 4) {
            float4 a = *(const float4*)&sH4[rr][k];
            float4 w = *(const float4*)&W3[(long)col * 32 + k];
            acc = fmaf(a.x, w.x, fmaf(a.y, w.y, fmaf(a.z, w.z, fmaf(a.w, w.w, acc))));
        }
        if (r0 + rr < M) out[(long)(r0 + rr) * 3 + col] = acc;
    }
}

// ---------------- launch ----------------

extern "C" void kernel_launch(void* const* d_in, const int* in_sizes, int n_in,
                              void* d_out, int out_size, void* d_ws, size_t ws_size,
                              hipStream_t stream) {
    const float* x   = (const float*)d_in[0];
    const int*   ei  = (const int*)d_in[1];
    const float* W_l = (const float*)d_in[2];
    const float* b_l = (const float*)d_in[3];
    const float* W_r = (const float*)d_in[4];
    const float* Wa  = (const float*)d_in[5];
    const float* ba  = (const float*)d_in[6];
    const float* W1  = (const float*)d_in[7];
    const float* b1  = (const float*)d_in[8];
    const float* W2  = (const float*)d_in[9];
    const float* b2  = (const float*)d_in[10];
    const float* W3  = (const float*)d_in[11];
    const float* b3  = (const float*)d_in[12];
    float* out = (float*)d_out;

    const int M = in_sizes[0] / D;   // 10000
    const int E = in_sizes[1] / 2;   // 320000
    const int* src = ei;
    const int* dst = ei + E;

    // workspace carve (16B-aligned chunks), ~33 MB total
    char* ws = (char*)d_ws;
    int*            deg     = (int*)ws;            ws += 40064;
    int*            offsets = (int*)ws;            ws += 40064;
    int*            cursor  = (int*)ws;            ws += 40064;
    int*            csr     = (int*)ws;            ws += (size_t)E * 4;
    unsigned short* Ah      = (unsigned short*)ws; ws += (size_t)M * 512 * 2;
    unsigned short* Al      = (unsigned short*)ws; ws += (size_t)M * 512 * 2;
    unsigned short* Bh      = (unsigned short*)ws; ws += (size_t)256 * 512 * 2;
    unsigned short* Bl      = (unsigned short*)ws; ws += (size_t)256 * 512 * 2;
    float*          h1      = (float*)ws;          ws += (size_t)M * 256 * 4;

    // CSR build
    zero_int<<<(M + 255) / 256, 256, 0, stream>>>(deg, M);
    degree_kernel<<<(E + 255) / 256, 256, 0, stream>>>(dst, deg, E);
    scan_kernel<<<1, 1024, 0, stream>>>(deg, offsets, cursor, M);
    bucket_kernel<<<(E + 255) / 256, 256, 0, stream>>>(src, dst, cursor, csr, E);

    // conversions (x-half of A, weights)
    int total4 = M * 64;  // M*256/4
    cvt_x_kernel<<<(total4 + 255) / 256, 256, 0, stream>>>(x, Ah, Al, total4);
    cvt_w_kernel<<<(32768 + 255) / 256, 256, 0, stream>>>(W_l, W_r, Bh, Bl);

    // mean aggregation (bf16-hi gather; writes agg-half of Ah/Al)
    agg_kernel<<<(M + 3) / 4, 256, 0, stream>>>(csr, offsets, Ah, Al, M);

    // layer 1 via split-bf16 MFMA
    gemm1_mfma<<<dim3((M + 63) / 64, 4), 256, 0, stream>>>(Ah, Al, Bh, Bl, b_l, h1, M);

    // layers 2..5 fused, 8 rows/block
    mlp_fused<<<(M + 7) / 8, 256, 0, stream>>>(h1, Wa, ba, W1, b1, W2, b2, W3, b3, out, M);
}

// Round 5
// 266.457 us; speedup vs baseline: 1.5530x; 1.5530x over previous
//
#include <hip/hip_runtime.h>

#define D 256

typedef short short8 __attribute__((ext_vector_type(8)));
typedef float f32x4 __attribute__((ext_vector_type(4)));

// bf16 helpers (RNE)
__device__ __forceinline__ unsigned short f2bf(float f) {
    unsigned int u = __float_as_uint(f);
    unsigned int r = (u + 0x7FFFu + ((u >> 16) & 1u)) >> 16;
    return (unsigned short)r;
}
__device__ __forceinline__ float bf2f(unsigned short h) {
    return __uint_as_float(((unsigned int)h) << 16);
}

// ---------------- small utils ----------------

__global__ void zero_int(int* __restrict__ p, int n) {
    int i = blockIdx.x * blockDim.x + threadIdx.x;
    if (i < n) p[i] = 0;
}

// ---------------- CSR build ----------------

__global__ void degree_kernel(const int* __restrict__ dst, int* __restrict__ deg, int E) {
    int e = blockIdx.x * blockDim.x + threadIdx.x;
    if (e < E) atomicAdd(&deg[dst[e]], 1);
}

__global__ __launch_bounds__(1024) void scan_kernel(const int* __restrict__ deg,
                                                    int* __restrict__ offsets,
                                                    int* __restrict__ cursor, int n) {
    const int CHUNK = 16;
    __shared__ int s[1024];
    int t = threadIdx.x;
    int base_idx = t * CHUNK;
    int vals[CHUNK];
    int local = 0;
#pragma unroll
    for (int i = 0; i < CHUNK; ++i) {
        int idx = base_idx + i;
        int v = (idx < n) ? deg[idx] : 0;
        vals[i] = v;
        local += v;
    }
    s[t] = local;
    __syncthreads();
    for (int off = 1; off < 1024; off <<= 1) {
        int v = (t >= off) ? s[t - off] : 0;
        __syncthreads();
        s[t] += v;
        __syncthreads();
    }
    int run = s[t] - local;
#pragma unroll
    for (int i = 0; i < CHUNK; ++i) {
        int idx = base_idx + i;
        if (idx < n) {
            offsets[idx] = run;
            cursor[idx]  = run;
            run += vals[i];
        }
    }
    if (t == 1023) offsets[n] = s[1023];
}

__global__ void bucket_kernel(const int* __restrict__ src, const int* __restrict__ dst,
                              int* __restrict__ cursor, int* __restrict__ csr, int E) {
    int e = blockIdx.x * blockDim.x + threadIdx.x;
    if (e < E) {
        int d = dst[e];
        int pos = atomicAdd(&cursor[d], 1);
        csr[pos] = src[e];
    }
}

// ---------------- conversions ----------------
// Ah/Al: [M][512] bf16; cols 0..255 = agg (filled by agg_kernel), 256..511 = x.
// Bh/Bl: [256][512]; row n = [W_l[n] | W_r[n]].

__global__ void cvt_x_kernel(const float* __restrict__ x,
                             unsigned short* __restrict__ Ah,
                             unsigned short* __restrict__ Al, int total4) {
    int i = blockIdx.x * blockDim.x + threadIdx.x;
    if (i >= total4) return;
    int m = i >> 6;
    int c = (i & 63) << 2;
    float4 v = *(const float4*)&x[(long)m * 256 + c];
    ushort4 h, l;
    h.x = f2bf(v.x); l.x = f2bf(v.x - bf2f(h.x));
    h.y = f2bf(v.y); l.y = f2bf(v.y - bf2f(h.y));
    h.z = f2bf(v.z); l.z = f2bf(v.z - bf2f(h.z));
    h.w = f2bf(v.w); l.w = f2bf(v.w - bf2f(h.w));
    *(ushort4*)&Ah[(long)m * 512 + 256 + c] = h;
    *(ushort4*)&Al[(long)m * 512 + 256 + c] = l;
}

__global__ void cvt_w_kernel(const float* __restrict__ W_l, const float* __restrict__ W_r,
                             unsigned short* __restrict__ Bh,
                             unsigned short* __restrict__ Bl) {
    int i = blockIdx.x * blockDim.x + threadIdx.x;
    if (i >= 32768) return;
    int n = i >> 7;
    int k4 = (i & 127) << 2;
    float4 v = (k4 < 256) ? *(const float4*)&W_l[(long)n * 256 + k4]
                          : *(const float4*)&W_r[(long)n * 256 + (k4 - 256)];
    ushort4 h, l;
    h.x = f2bf(v.x); l.x = f2bf(v.x - bf2f(h.x));
    h.y = f2bf(v.y); l.y = f2bf(v.y - bf2f(h.y));
    h.z = f2bf(v.z); l.z = f2bf(v.z - bf2f(h.z));
    h.w = f2bf(v.w); l.w = f2bf(v.w - bf2f(h.w));
    *(ushort4*)&Bh[(long)n * 512 + k4] = h;
    *(ushort4*)&Bl[(long)n * 512 + k4] = l;
}

// Wa (128x256) -> bf16 hi/lo
__global__ void cvt_wa_kernel(const float* __restrict__ Wa,
                              unsigned short* __restrict__ Wah,
                              unsigned short* __restrict__ Wal) {
    int i = blockIdx.x * blockDim.x + threadIdx.x;
    if (i >= 8192) return;
    int c = i << 2;
    float4 v = *(const float4*)&Wa[c];
    ushort4 h, l;
    h.x = f2bf(v.x); l.x = f2bf(v.x - bf2f(h.x));
    h.y = f2bf(v.y); l.y = f2bf(v.y - bf2f(h.y));
    h.z = f2bf(v.z); l.z = f2bf(v.z - bf2f(h.z));
    h.w = f2bf(v.w); l.w = f2bf(v.w - bf2f(h.w));
    *(ushort4*)&Wah[c] = h;
    *(ushort4*)&Wal[c] = l;
}

// ---------------- aggregation: one wave per node, bf16-hi gather ----------------

__global__ __launch_bounds__(256) void agg_kernel(const int* __restrict__ csr,
                                                  const int* __restrict__ offsets,
                                                  unsigned short* __restrict__ Ah,
                                                  unsigned short* __restrict__ Al, int M) {
    int node = (blockIdx.x * 256 + threadIdx.x) >> 6;
    int lane = threadIdx.x & 63;
    if (node >= M) return;
    int start = offsets[node];
    int end   = offsets[node + 1];
    const unsigned short* xb = Ah + 256 + lane * 4;  // row stride 512
    float4 acc = {0.f, 0.f, 0.f, 0.f};
    int e = start;
    for (; e + 4 <= end; e += 4) {
        int s0 = csr[e + 0], s1 = csr[e + 1], s2 = csr[e + 2], s3 = csr[e + 3];
        ushort4 v0 = *(const ushort4*)(xb + (long)s0 * 512);
        ushort4 v1 = *(const ushort4*)(xb + (long)s1 * 512);
        ushort4 v2 = *(const ushort4*)(xb + (long)s2 * 512);
        ushort4 v3 = *(const ushort4*)(xb + (long)s3 * 512);
        acc.x += bf2f(v0.x) + bf2f(v1.x) + bf2f(v2.x) + bf2f(v3.x);
        acc.y += bf2f(v0.y) + bf2f(v1.y) + bf2f(v2.y) + bf2f(v3.y);
        acc.z += bf2f(v0.z) + bf2f(v1.z) + bf2f(v2.z) + bf2f(v3.z);
        acc.w += bf2f(v0.w) + bf2f(v1.w) + bf2f(v2.w) + bf2f(v3.w);
    }
    for (; e < end; ++e) {
        int s = csr[e];
        ushort4 v = *(const ushort4*)(xb + (long)s * 512);
        acc.x += bf2f(v.x); acc.y += bf2f(v.y); acc.z += bf2f(v.z); acc.w += bf2f(v.w);
    }
    int cnt = end - start;
    float sc = 1.0f / (float)(cnt > 0 ? cnt : 1);
    acc.x *= sc; acc.y *= sc; acc.z *= sc; acc.w *= sc;
    ushort4 h, l;
    h.x = f2bf(acc.x); l.x = f2bf(acc.x - bf2f(h.x));
    h.y = f2bf(acc.y); l.y = f2bf(acc.y - bf2f(h.y));
    h.z = f2bf(acc.z); l.z = f2bf(acc.z - bf2f(h.z));
    h.w = f2bf(acc.w); l.w = f2bf(acc.w - bf2f(h.w));
    *(ushort4*)&Ah[(long)node * 512 + lane * 4] = h;
    *(ushort4*)&Al[(long)node * 512 + lane * 4] = l;
}

// ---------------- layer 1: split-bf16 MFMA GEMM -> h1 (bf16 hi/lo) ----------------
// h1 = relu(A @ B^T + b_l), A=[agg|x] (M x 512), B=[W_l|W_r] (256 x 512).

__global__ __launch_bounds__(256) void gemm1_mfma(const unsigned short* __restrict__ Ah,
                                                  const unsigned short* __restrict__ Al,
                                                  const unsigned short* __restrict__ Bh,
                                                  const unsigned short* __restrict__ Bl,
                                                  const float* __restrict__ bias,
                                                  unsigned short* __restrict__ h1h,
                                                  unsigned short* __restrict__ h1l, int M) {
    const int tid  = threadIdx.x;
    const int wave = tid >> 6;
    const int lane = tid & 63;
    const int l16  = lane & 15;
    const int quad = lane >> 4;
    const int m_base = blockIdx.x * 64 + wave * 16;
    const int n_base = blockIdx.y * 64;

    int rowA = m_base + l16;
    if (rowA > M - 1) rowA = M - 1;
    const unsigned short* pAh = Ah + (long)rowA * 512 + quad * 8;
    const unsigned short* pAl = Al + (long)rowA * 512 + quad * 8;

    f32x4 acc[4] = {};

#pragma unroll 2
    for (int kk = 0; kk < 512; kk += 32) {
        short8 ah = *(const short8*)(pAh + kk);
        short8 al = *(const short8*)(pAl + kk);
#pragma unroll
        for (int t = 0; t < 4; ++t) {
            long off = (long)(n_base + t * 16 + l16) * 512 + quad * 8 + kk;
            short8 bh = *(const short8*)(Bh + off);
            short8 bl = *(const short8*)(Bl + off);
            acc[t] = __builtin_amdgcn_mfma_f32_16x16x32_bf16(ah, bh, acc[t], 0, 0, 0);
            acc[t] = __builtin_amdgcn_mfma_f32_16x16x32_bf16(ah, bl, acc[t], 0, 0, 0);
            acc[t] = __builtin_amdgcn_mfma_f32_16x16x32_bf16(al, bh, acc[t], 0, 0, 0);
        }
    }

    // C/D layout: col = lane&15, row = quad*4 + reg
#pragma unroll
    for (int t = 0; t < 4; ++t) {
        int n = n_base + t * 16 + l16;
        float bv = bias[n];
#pragma unroll
        for (int r = 0; r < 4; ++r) {
            int m = m_base + quad * 4 + r;
            if (m < M) {
                float v = fmaxf(acc[t][r] + bv, 0.f);
                unsigned short h = f2bf(v);
                h1h[(long)m * 256 + n] = h;
                h1l[(long)m * 256 + n] = f2bf(v - bf2f(h));
            }
        }
    }
}

// ---------------- layer 2: split-bf16 MFMA, 1-wave blocks ----------------
// h2 = relu(h1 @ Wa^T + ba), h1: M x 256 bf16 hi/lo, Wa: 128 x 256.
// grid = (M/16, 2); wave owns 16 rows x 64 cols.

__global__ __launch_bounds__(64) void gemm2_mfma(const unsigned short* __restrict__ h1h,
                                                 const unsigned short* __restrict__ h1l,
                                                 const unsigned short* __restrict__ Wah,
                                                 const unsigned short* __restrict__ Wal,
                                                 const float* __restrict__ bias,
                                                 float* __restrict__ h2, int M) {
    const int lane = threadIdx.x;
    const int l16  = lane & 15;
    const int quad = lane >> 4;
    const int m_base = blockIdx.x * 16;
    const int n_base = blockIdx.y * 64;

    int rowA = m_base + l16;
    if (rowA > M - 1) rowA = M - 1;
    const unsigned short* pAh = h1h + (long)rowA * 256 + quad * 8;
    const unsigned short* pAl = h1l + (long)rowA * 256 + quad * 8;

    f32x4 acc[4] = {};

#pragma unroll 2
    for (int kk = 0; kk < 256; kk += 32) {
        short8 ah = *(const short8*)(pAh + kk);
        short8 al = *(const short8*)(pAl + kk);
#pragma unroll
        for (int t = 0; t < 4; ++t) {
            long off = (long)(n_base + t * 16 + l16) * 256 + quad * 8 + kk;
            short8 bh = *(const short8*)(Wah + off);
            short8 bl = *(const short8*)(Wal + off);
            acc[t] = __builtin_amdgcn_mfma_f32_16x16x32_bf16(ah, bh, acc[t], 0, 0, 0);
            acc[t] = __builtin_amdgcn_mfma_f32_16x16x32_bf16(ah, bl, acc[t], 0, 0, 0);
            acc[t] = __builtin_amdgcn_mfma_f32_16x16x32_bf16(al, bh, acc[t], 0, 0, 0);
        }
    }

#pragma unroll
    for (int t = 0; t < 4; ++t) {
        int n = n_base + t * 16 + l16;
        float bv = bias[n];
#pragma unroll
        for (int r = 0; r < 4; ++r) {
            int m = m_base + quad * 4 + r;
            if (m < M) h2[(long)m * 128 + n] = fmaxf(acc[t][r] + bv, 0.f);
        }
    }
}

// ---------------- layers 3..5: 32 rows/block, transposed-LDS weights ----------------
// Transposed [k][out] layout => lanes with different out-group hit different banks
// (2-way aliasing only, free per m136); [out][k] would be 16-way conflicted.

__global__ __launch_bounds__(512) void mlp345(const float* __restrict__ h2,
                                              const float* __restrict__ W1,
                                              const float* __restrict__ b1,
                                              const float* __restrict__ W2,
                                              const float* __restrict__ b2,
                                              const float* __restrict__ W3,
                                              const float* __restrict__ b3,
                                              float* __restrict__ out, int M) {
    __shared__ float sW1T[128][64];  // 32 KB, [k][o]
    __shared__ float sW2T[64][32];   // 8 KB
    __shared__ float sW3T[32][4];    // 512 B
    __shared__ float sb1[64], sb2[32], sb3[4];
    __shared__ float sH2[32][132];
    __shared__ float sH3[32][68];
    __shared__ float sH4[32][36];

    const int tid = threadIdx.x;
    const int r0 = blockIdx.x * 32;

    for (int i = tid; i < 64 * 128; i += 512) { int o = i >> 7, k = i & 127; sW1T[k][o] = W1[i]; }
    for (int i = tid; i < 32 * 64; i += 512)  { int o = i >> 6, k = i & 63;  sW2T[k][o] = W2[i]; }
    if (tid < 96) { int o = tid >> 5, k = tid & 31; sW3T[k][o] = W3[tid]; }
    if (tid < 64) sb1[tid] = b1[tid];
    else if (tid < 96) sb2[tid - 64] = b2[tid - 64];
    else if (tid < 100) sb3[tid - 96] = b3[tid - 96];

    // stage h2 tile: 32 x 128 floats
    for (int i = tid; i < 32 * 32; i += 512) {
        int rr = i >> 5;
        int c = (i & 31) << 2;
        float4 v = {0.f, 0.f, 0.f, 0.f};
        if (r0 + rr < M) v = *(const float4*)&h2[(long)(r0 + rr) * 128 + c];
        *(float4*)&sH2[rr][c] = v;
    }
    __syncthreads();

    const int r = tid >> 4;   // 0..31
    const int s = tid & 15;   // 0..15

    // layer 3: outs s*4..+3, K=128
    {
        float4 acc = *(const float4*)&sb1[s * 4];
        for (int k = 0; k < 128; k += 4) {
            float4 a = *(const float4*)&sH2[r][k];
            float4 w0 = *(const float4*)&sW1T[k + 0][s * 4];
            float4 w1 = *(const float4*)&sW1T[k + 1][s * 4];
            float4 w2 = *(const float4*)&sW1T[k + 2][s * 4];
            float4 w3 = *(const float4*)&sW1T[k + 3][s * 4];
            acc.x = fmaf(a.x, w0.x, fmaf(a.y, w1.x, fmaf(a.z, w2.x, fmaf(a.w, w3.x, acc.x))));
            acc.y = fmaf(a.x, w0.y, fmaf(a.y, w1.y, fmaf(a.z, w2.y, fmaf(a.w, w3.y, acc.y))));
            acc.z = fmaf(a.x, w0.z, fmaf(a.y, w1.z, fmaf(a.z, w2.z, fmaf(a.w, w3.z, acc.z))));
            acc.w = fmaf(a.x, w0.w, fmaf(a.y, w1.w, fmaf(a.z, w2.w, fmaf(a.w, w3.w, acc.w))));
        }
        float4 o;
        o.x = fmaxf(acc.x, 0.f); o.y = fmaxf(acc.y, 0.f);
        o.z = fmaxf(acc.z, 0.f); o.w = fmaxf(acc.w, 0.f);
        *(float4*)&sH3[r][s * 4] = o;
    }
    __syncthreads();

    // layer 4: outs s*2..+1, K=64
    {
        float a0 = sb2[s * 2], a1 = sb2[s * 2 + 1];
        for (int k = 0; k < 64; k += 4) {
            float4 a = *(const float4*)&sH3[r][k];
            float2 w0 = *(const float2*)&sW2T[k + 0][s * 2];
            float2 w1 = *(const float2*)&sW2T[k + 1][s * 2];
            float2 w2 = *(const float2*)&sW2T[k + 2][s * 2];
            float2 w3 = *(const float2*)&sW2T[k + 3][s * 2];
            a0 = fmaf(a.x, w0.x, fmaf(a.y, w1.x, fmaf(a.z, w2.x, fmaf(a.w, w3.x, a0))));
            a1 = fmaf(a.x, w0.y, fmaf(a.y, w1.y, fmaf(a.z, w2.y, fmaf(a.w, w3.y, a1))));
        }
        float2 o;
        o.x = fmaxf(a0, 0.f);
        o.y = fmaxf(a1, 0.f);
        *(float2*)&sH4[r][s * 2] = o;
    }
    __syncthreads();

    // layer 5: 3 outs per row
    if (s < 3) {
        float acc = sb3[s];
        for (int k = 0; k < 32; k += 4) {
            float4 a = *(const float4*)&sH4[r][k];
            acc = fmaf(a.x, sW3T[k + 0][s],
                  fmaf(a.y, sW3T[k + 1][s],
                  fmaf(a.z, sW3T[k + 2][s],
                  fmaf(a.w, sW3T[k + 3][s], acc))));
        }
        if (r0 + r < M) out[(long)(r0 + r) * 3 + s] = acc;
    }
}

// ---------------- launch ----------------

extern "C" void kernel_launch(void* const* d_in, const int* in_sizes, int n_in,
                              void* d_out, int out_size, void* d_ws, size_t ws_size,
                              hipStream_t stream) {
    const float* x   = (const float*)d_in[0];
    const int*   ei  = (const int*)d_in[1];
    const float* W_l = (const float*)d_in[2];
    const float* b_l = (const float*)d_in[3];
    const float* W_r = (const float*)d_in[4];
    const float* Wa  = (const float*)d_in[5];
    const float* ba  = (const float*)d_in[6];
    const float* W1  = (const float*)d_in[7];
    const float* b1  = (const float*)d_in[8];
    const float* W2  = (const float*)d_in[9];
    const float* b2  = (const float*)d_in[10];
    const float* W3  = (const float*)d_in[11];
    const float* b3  = (const float*)d_in[12];
    float* out = (float*)d_out;

    const int M = in_sizes[0] / D;   // 10000
    const int E = in_sizes[1] / 2;   // 320000
    const int* src = ei;
    const int* dst = ei + E;

    // workspace carve (16B-aligned chunks), ~38.4 MB
    char* ws = (char*)d_ws;
    int*            deg     = (int*)ws;            ws += 40064;
    int*            offsets = (int*)ws;            ws += 40064;
    int*            cursor  = (int*)ws;            ws += 40064;
    int*            csr     = (int*)ws;            ws += (size_t)E * 4;
    unsigned short* Ah      = (unsigned short*)ws; ws += (size_t)M * 512 * 2;
    unsigned short* Al      = (unsigned short*)ws; ws += (size_t)M * 512 * 2;
    unsigned short* Bh      = (unsigned short*)ws; ws += (size_t)256 * 512 * 2;
    unsigned short* Bl      = (unsigned short*)ws; ws += (size_t)256 * 512 * 2;
    unsigned short* Wah     = (unsigned short*)ws; ws += (size_t)128 * 256 * 2;
    unsigned short* Wal     = (unsigned short*)ws; ws += (size_t)128 * 256 * 2;
    unsigned short* h1h     = (unsigned short*)ws; ws += (size_t)M * 256 * 2;
    unsigned short* h1l     = (unsigned short*)ws; ws += (size_t)M * 256 * 2;
    float*          h2      = (float*)ws;          ws += (size_t)M * 128 * 4;

    // CSR build
    zero_int<<<(M + 255) / 256, 256, 0, stream>>>(deg, M);
    degree_kernel<<<(E + 255) / 256, 256, 0, stream>>>(dst, deg, E);
    scan_kernel<<<1, 1024, 0, stream>>>(deg, offsets, cursor, M);
    bucket_kernel<<<(E + 255) / 256, 256, 0, stream>>>(src, dst, cursor, csr, E);

    // conversions
    int total4 = M * 64;
    cvt_x_kernel<<<(total4 + 255) / 256, 256, 0, stream>>>(x, Ah, Al, total4);
    cvt_w_kernel<<<(32768 + 255) / 256, 256, 0, stream>>>(W_l, W_r, Bh, Bl);
    cvt_wa_kernel<<<(8192 + 255) / 256, 256, 0, stream>>>(Wa, Wah, Wal);

    // mean aggregation
    agg_kernel<<<(M + 3) / 4, 256, 0, stream>>>(csr, offsets, Ah, Al, M);

    // layer 1 (MFMA) -> h1 bf16 hi/lo
    gemm1_mfma<<<dim3((M + 63) / 64, 4), 256, 0, stream>>>(Ah, Al, Bh, Bl, b_l, h1h, h1l, M);

    // layer 2 (MFMA) -> h2 fp32
    gemm2_mfma<<<dim3((M + 15) / 16, 2), 64, 0, stream>>>(h1h, h1l, Wah, Wal, ba, h2, M);

    // layers 3..5
    mlp345<<<(M + 31) / 32, 512, 0, stream>>>(h2, W1, b1, W2, b2, W3, b3, out, M);
}

// Round 6
// 222.806 us; speedup vs baseline: 1.8573x; 1.1959x over previous
//
#include <hip/hip_runtime.h>

#define D 256

typedef short short8 __attribute__((ext_vector_type(8)));
typedef float f32x4 __attribute__((ext_vector_type(4)));

// bf16 helpers (RNE)
__device__ __forceinline__ unsigned short f2bf(float f) {
    unsigned int u = __float_as_uint(f);
    unsigned int r = (u + 0x7FFFu + ((u >> 16) & 1u)) >> 16;
    return (unsigned short)r;
}
__device__ __forceinline__ float bf2f(unsigned short h) {
    return __uint_as_float(((unsigned int)h) << 16);
}

// ---------------- small utils ----------------

__global__ void zero_int(int* __restrict__ p, int n) {
    int i = blockIdx.x * blockDim.x + threadIdx.x;
    if (i < n) p[i] = 0;
}

// ---------------- CSR build ----------------

__global__ void degree_kernel(const int* __restrict__ dst, int* __restrict__ deg, int E) {
    int e = blockIdx.x * blockDim.x + threadIdx.x;
    if (e < E) atomicAdd(&deg[dst[e]], 1);
}

__global__ __launch_bounds__(1024) void scan_kernel(const int* __restrict__ deg,
                                                    int* __restrict__ offsets,
                                                    int* __restrict__ cursor, int n) {
    const int CHUNK = 16;
    __shared__ int s[1024];
    int t = threadIdx.x;
    int base_idx = t * CHUNK;
    int vals[CHUNK];
    int local = 0;
#pragma unroll
    for (int i = 0; i < CHUNK; ++i) {
        int idx = base_idx + i;
        int v = (idx < n) ? deg[idx] : 0;
        vals[i] = v;
        local += v;
    }
    s[t] = local;
    __syncthreads();
    for (int off = 1; off < 1024; off <<= 1) {
        int v = (t >= off) ? s[t - off] : 0;
        __syncthreads();
        s[t] += v;
        __syncthreads();
    }
    int run = s[t] - local;
#pragma unroll
    for (int i = 0; i < CHUNK; ++i) {
        int idx = base_idx + i;
        if (idx < n) {
            offsets[idx] = run;
            cursor[idx]  = run;
            run += vals[i];
        }
    }
    if (t == 1023) offsets[n] = s[1023];
}

__global__ void bucket_kernel(const int* __restrict__ src, const int* __restrict__ dst,
                              int* __restrict__ cursor, int* __restrict__ csr, int E) {
    int e = blockIdx.x * blockDim.x + threadIdx.x;
    if (e < E) {
        int d = dst[e];
        int pos = atomicAdd(&cursor[d], 1);
        csr[pos] = src[e];
    }
}

// ---------------- conversions ----------------
// Ah/Al: [M][512] bf16; cols 0..255 = agg (filled by agg_kernel), 256..511 = x.
// Bh/Bl: [256][512]; row n = [W_l[n] | W_r[n]].

__global__ void cvt_x_kernel(const float* __restrict__ x,
                             unsigned short* __restrict__ Ah,
                             unsigned short* __restrict__ Al, int total4) {
    int i = blockIdx.x * blockDim.x + threadIdx.x;
    if (i >= total4) return;
    int m = i >> 6;
    int c = (i & 63) << 2;
    float4 v = *(const float4*)&x[(long)m * 256 + c];
    ushort4 h, l;
    h.x = f2bf(v.x); l.x = f2bf(v.x - bf2f(h.x));
    h.y = f2bf(v.y); l.y = f2bf(v.y - bf2f(h.y));
    h.z = f2bf(v.z); l.z = f2bf(v.z - bf2f(h.z));
    h.w = f2bf(v.w); l.w = f2bf(v.w - bf2f(h.w));
    *(ushort4*)&Ah[(long)m * 512 + 256 + c] = h;
    *(ushort4*)&Al[(long)m * 512 + 256 + c] = l;
}

__global__ void cvt_w_kernel(const float* __restrict__ W_l, const float* __restrict__ W_r,
                             unsigned short* __restrict__ Bh,
                             unsigned short* __restrict__ Bl) {
    int i = blockIdx.x * blockDim.x + threadIdx.x;
    if (i >= 32768) return;
    int n = i >> 7;
    int k4 = (i & 127) << 2;
    float4 v = (k4 < 256) ? *(const float4*)&W_l[(long)n * 256 + k4]
                          : *(const float4*)&W_r[(long)n * 256 + (k4 - 256)];
    ushort4 h, l;
    h.x = f2bf(v.x); l.x = f2bf(v.x - bf2f(h.x));
    h.y = f2bf(v.y); l.y = f2bf(v.y - bf2f(h.y));
    h.z = f2bf(v.z); l.z = f2bf(v.z - bf2f(h.z));
    h.w = f2bf(v.w); l.w = f2bf(v.w - bf2f(h.w));
    *(ushort4*)&Bh[(long)n * 512 + k4] = h;
    *(ushort4*)&Bl[(long)n * 512 + k4] = l;
}

// Wa (128x256) -> bf16 hi/lo
__global__ void cvt_wa_kernel(const float* __restrict__ Wa,
                              unsigned short* __restrict__ Wah,
                              unsigned short* __restrict__ Wal) {
    int i = blockIdx.x * blockDim.x + threadIdx.x;
    if (i >= 8192) return;
    int c = i << 2;
    float4 v = *(const float4*)&Wa[c];
    ushort4 h, l;
    h.x = f2bf(v.x); l.x = f2bf(v.x - bf2f(h.x));
    h.y = f2bf(v.y); l.y = f2bf(v.y - bf2f(h.y));
    h.z = f2bf(v.z); l.z = f2bf(v.z - bf2f(h.z));
    h.w = f2bf(v.w); l.w = f2bf(v.w - bf2f(h.w));
    *(ushort4*)&Wah[c] = h;
    *(ushort4*)&Wal[c] = l;
}

// ---------------- aggregation: one wave per node, bf16-hi gather ----------------

__global__ __launch_bounds__(256) void agg_kernel(const int* __restrict__ csr,
                                                  const int* __restrict__ offsets,
                                                  unsigned short* __restrict__ Ah,
                                                  unsigned short* __restrict__ Al, int M) {
    int node = (blockIdx.x * 256 + threadIdx.x) >> 6;
    int lane = threadIdx.x & 63;
    if (node >= M) return;
    int start = offsets[node];
    int end   = offsets[node + 1];
    const unsigned short* xb = Ah + 256 + lane * 4;  // row stride 512
    float4 acc = {0.f, 0.f, 0.f, 0.f};
    int e = start;
    for (; e + 4 <= end; e += 4) {
        int s0 = csr[e + 0], s1 = csr[e + 1], s2 = csr[e + 2], s3 = csr[e + 3];
        ushort4 v0 = *(const ushort4*)(xb + (long)s0 * 512);
        ushort4 v1 = *(const ushort4*)(xb + (long)s1 * 512);
        ushort4 v2 = *(const ushort4*)(xb + (long)s2 * 512);
        ushort4 v3 = *(const ushort4*)(xb + (long)s3 * 512);
        acc.x += bf2f(v0.x) + bf2f(v1.x) + bf2f(v2.x) + bf2f(v3.x);
        acc.y += bf2f(v0.y) + bf2f(v1.y) + bf2f(v2.y) + bf2f(v3.y);
        acc.z += bf2f(v0.z) + bf2f(v1.z) + bf2f(v2.z) + bf2f(v3.z);
        acc.w += bf2f(v0.w) + bf2f(v1.w) + bf2f(v2.w) + bf2f(v3.w);
    }
    for (; e < end; ++e) {
        int s = csr[e];
        ushort4 v = *(const ushort4*)(xb + (long)s * 512);
        acc.x += bf2f(v.x); acc.y += bf2f(v.y); acc.z += bf2f(v.z); acc.w += bf2f(v.w);
    }
    int cnt = end - start;
    float sc = 1.0f / (float)(cnt > 0 ? cnt : 1);
    acc.x *= sc; acc.y *= sc; acc.z *= sc; acc.w *= sc;
    ushort4 h, l;
    h.x = f2bf(acc.x); l.x = f2bf(acc.x - bf2f(h.x));
    h.y = f2bf(acc.y); l.y = f2bf(acc.y - bf2f(h.y));
    h.z = f2bf(acc.z); l.z = f2bf(acc.z - bf2f(h.z));
    h.w = f2bf(acc.w); l.w = f2bf(acc.w - bf2f(h.w));
    *(ushort4*)&Ah[(long)node * 512 + lane * 4] = h;
    *(ushort4*)&Al[(long)node * 512 + lane * 4] = l;
}

// ---------------- unified split-bf16 MFMA GEMM with LDS-staged B ----------------
// C = relu(A @ B^T + bias). A: [M][K] bf16 hi/lo, B: [N][K] bf16 hi/lo.
// Block: 4 waves = 64 rows x 64 cols; B-tile (64 cols x BK=64) LDS double-buffered,
// shared across the 4 waves (kills the per-wave B redundancy seen in R5).
// 72-short LDS row stride => 36-dword stride => 2-way bank aliasing only (free, m136).
// OUT_BF16: store hi/lo bf16 planes (for the next MFMA layer); else fp32.

template <int K, int NB, bool OUT_BF16>
__global__ __launch_bounds__(256) void gemm_mfma(const unsigned short* __restrict__ Ah,
                                                 const unsigned short* __restrict__ Al,
                                                 const unsigned short* __restrict__ Bh,
                                                 const unsigned short* __restrict__ Bl,
                                                 const float* __restrict__ bias,
                                                 unsigned short* __restrict__ Ch,
                                                 unsigned short* __restrict__ Cl,
                                                 float* __restrict__ Cf, int M) {
    constexpr int NC = K / 64;
    __shared__ __align__(16) unsigned short sBh[2][64][72];
    __shared__ __align__(16) unsigned short sBl[2][64][72];

    const int tid  = threadIdx.x;
    const int wave = tid >> 6;
    const int lane = tid & 63;
    const int l16  = lane & 15;
    const int quad = lane >> 4;
    const int m_base = blockIdx.x * 64 + wave * 16;
    const int n0 = blockIdx.y * 64;

    int rowA = m_base + l16;
    if (rowA > M - 1) rowA = M - 1;  // clamp; stores guarded below
    const unsigned short* pAh = Ah + (long)rowA * K + quad * 8;
    const unsigned short* pAl = Al + (long)rowA * K + quad * 8;

    // stage B chunk c into LDS buffer c&1 (256 threads x 2 iters x 16 B per plane)
    auto stage = [&](int c) {
        const int buf = c & 1;
        const int kk = c * 64;
#pragma unroll
        for (int i = 0; i < 2; ++i) {
            int idx = tid + i * 256;      // 0..511
            int col = idx >> 3;
            int seg = (idx & 7) * 8;      // short offset, 16B granular
            *(short8*)&sBh[buf][col][seg] = *(const short8*)&Bh[(long)(n0 + col) * K + kk + seg];
            *(short8*)&sBl[buf][col][seg] = *(const short8*)&Bl[(long)(n0 + col) * K + kk + seg];
        }
    };

    short8 a_h[2][2], a_l[2][2];  // [buf][kstep]
    auto loadA = [&](int c) {
        const int buf = c & 1;
#pragma unroll
        for (int ks = 0; ks < 2; ++ks) {
            a_h[buf][ks] = *(const short8*)(pAh + c * 64 + ks * 32);
            a_l[buf][ks] = *(const short8*)(pAl + c * 64 + ks * 32);
        }
    };

    f32x4 acc[4] = {};

    stage(0);
    loadA(0);
    __syncthreads();
#pragma unroll
    for (int c = 0; c < NC; ++c) {
        if (c + 1 < NC) { stage(c + 1); loadA(c + 1); }
        const int buf = c & 1;
#pragma unroll
        for (int ks = 0; ks < 2; ++ks) {
            short8 ah = a_h[buf][ks];
            short8 al = a_l[buf][ks];
#pragma unroll
            for (int t = 0; t < 4; ++t) {
                short8 bh = *(const short8*)&sBh[buf][t * 16 + l16][ks * 32 + quad * 8];
                short8 bl = *(const short8*)&sBl[buf][t * 16 + l16][ks * 32 + quad * 8];
                acc[t] = __builtin_amdgcn_mfma_f32_16x16x32_bf16(ah, bh, acc[t], 0, 0, 0);
                acc[t] = __builtin_amdgcn_mfma_f32_16x16x32_bf16(ah, bl, acc[t], 0, 0, 0);
                acc[t] = __builtin_amdgcn_mfma_f32_16x16x32_bf16(al, bh, acc[t], 0, 0, 0);
            }
        }
        __syncthreads();
    }

    // C/D layout: col = lane&15, row = quad*4 + reg
#pragma unroll
    for (int t = 0; t < 4; ++t) {
        int n = n0 + t * 16 + l16;
        float bv = bias[n];
#pragma unroll
        for (int r = 0; r < 4; ++r) {
            int m = m_base + quad * 4 + r;
            if (m < M) {
                float v = fmaxf(acc[t][r] + bv, 0.f);
                if constexpr (OUT_BF16) {
                    unsigned short h = f2bf(v);
                    Ch[(long)m * NB + n] = h;
                    Cl[(long)m * NB + n] = f2bf(v - bf2f(h));
                } else {
                    Cf[(long)m * NB + n] = v;
                }
            }
        }
    }
}

// ---------------- layers 3..5: 32 rows/block, transposed-LDS weights ----------------

__global__ __launch_bounds__(512) void mlp345(const float* __restrict__ h2,
                                              const float* __restrict__ W1,
                                              const float* __restrict__ b1,
                                              const float* __restrict__ W2,
                                              const float* __restrict__ b2,
                                              const float* __restrict__ W3,
                                              const float* __restrict__ b3,
                                              float* __restrict__ out, int M) {
    __shared__ float sW1T[128][64];  // 32 KB, [k][o]
    __shared__ float sW2T[64][32];   // 8 KB
    __shared__ float sW3T[32][4];    // 512 B
    __shared__ float sb1[64], sb2[32], sb3[4];
    __shared__ float sH2[32][132];
    __shared__ float sH3[32][68];
    __shared__ float sH4[32][36];

    const int tid = threadIdx.x;
    const int r0 = blockIdx.x * 32;

    for (int i = tid; i < 64 * 128; i += 512) { int o = i >> 7, k = i & 127; sW1T[k][o] = W1[i]; }
    for (int i = tid; i < 32 * 64; i += 512)  { int o = i >> 6, k = i & 63;  sW2T[k][o] = W2[i]; }
    if (tid < 96) { int o = tid >> 5, k = tid & 31; sW3T[k][o] = W3[tid]; }
    if (tid < 64) sb1[tid] = b1[tid];
    else if (tid < 96) sb2[tid - 64] = b2[tid - 64];
    else if (tid < 100) sb3[tid - 96] = b3[tid - 96];

    for (int i = tid; i < 32 * 32; i += 512) {
        int rr = i >> 5;
        int c = (i & 31) << 2;
        float4 v = {0.f, 0.f, 0.f, 0.f};
        if (r0 + rr < M) v = *(const float4*)&h2[(long)(r0 + rr) * 128 + c];
        *(float4*)&sH2[rr][c] = v;
    }
    __syncthreads();

    const int r = tid >> 4;   // 0..31
    const int s = tid & 15;   // 0..15

    // layer 3: outs s*4..+3, K=128
    {
        float4 acc = *(const float4*)&sb1[s * 4];
        for (int k = 0; k < 128; k += 4) {
            float4 a = *(const float4*)&sH2[r][k];
            float4 w0 = *(const float4*)&sW1T[k + 0][s * 4];
            float4 w1 = *(const float4*)&sW1T[k + 1][s * 4];
            float4 w2 = *(const float4*)&sW1T[k + 2][s * 4];
            float4 w3 = *(const float4*)&sW1T[k + 3][s * 4];
            acc.x = fmaf(a.x, w0.x, fmaf(a.y, w1.x, fmaf(a.z, w2.x, fmaf(a.w, w3.x, acc.x))));
            acc.y = fmaf(a.x, w0.y, fmaf(a.y, w1.y, fmaf(a.z, w2.y, fmaf(a.w, w3.y, acc.y))));
            acc.z = fmaf(a.x, w0.z, fmaf(a.y, w1.z, fmaf(a.z, w2.z, fmaf(a.w, w3.z, acc.z))));
            acc.w = fmaf(a.x, w0.w, fmaf(a.y, w1.w, fmaf(a.z, w2.w, fmaf(a.w, w3.w, acc.w))));
        }
        float4 o;
        o.x = fmaxf(acc.x, 0.f); o.y = fmaxf(acc.y, 0.f);
        o.z = fmaxf(acc.z, 0.f); o.w = fmaxf(acc.w, 0.f);
        *(float4*)&sH3[r][s * 4] = o;
    }
    __syncthreads();

    // layer 4: outs s*2..+1, K=64
    {
        float a0 = sb2[s * 2], a1 = sb2[s * 2 + 1];
        for (int k = 0; k < 64; k += 4) {
            float4 a = *(const float4*)&sH3[r][k];
            float2 w0 = *(const float2*)&sW2T[k + 0][s * 2];
            float2 w1 = *(const float2*)&sW2T[k + 1][s * 2];
            float2 w2 = *(const float2*)&sW2T[k + 2][s * 2];
            float2 w3 = *(const float2*)&sW2T[k + 3][s * 2];
            a0 = fmaf(a.x, w0.x, fmaf(a.y, w1.x, fmaf(a.z, w2.x, fmaf(a.w, w3.x, a0))));
            a1 = fmaf(a.x, w0.y, fmaf(a.y, w1.y, fmaf(a.z, w2.y, fmaf(a.w, w3.y, a1))));
        }
        float2 o;
        o.x = fmaxf(a0, 0.f);
        o.y = fmaxf(a1, 0.f);
        *(float2*)&sH4[r][s * 2] = o;
    }
    __syncthreads();

    // layer 5: 3 outs per row
    if (s < 3) {
        float acc = sb3[s];
        for (int k = 0; k < 32; k += 4) {
            float4 a = *(const float4*)&sH4[r][k];
            acc = fmaf(a.x, sW3T[k + 0][s],
                  fmaf(a.y, sW3T[k + 1][s],
                  fmaf(a.z, sW3T[k + 2][s],
                  fmaf(a.w, sW3T[k + 3][s], acc))));
        }
        if (r0 + r < M) out[(long)(r0 + r) * 3 + s] = acc;
    }
}

// ---------------- launch ----------------

extern "C" void kernel_launch(void* const* d_in, const int* in_sizes, int n_in,
                              void* d_out, int out_size, void* d_ws, size_t ws_size,
                              hipStream_t stream) {
    const float* x   = (const float*)d_in[0];
    const int*   ei  = (const int*)d_in[1];
    const float* W_l = (const float*)d_in[2];
    const float* b_l = (const float*)d_in[3];
    const float* W_r = (const float*)d_in[4];
    const float* Wa  = (const float*)d_in[5];
    const float* ba  = (const float*)d_in[6];
    const float* W1  = (const float*)d_in[7];
    const float* b1  = (const float*)d_in[8];
    const float* W2  = (const float*)d_in[9];
    const float* b2  = (const float*)d_in[10];
    const float* W3  = (const float*)d_in[11];
    const float* b3  = (const float*)d_in[12];
    float* out = (float*)d_out;

    const int M = in_sizes[0] / D;   // 10000
    const int E = in_sizes[1] / 2;   // 320000
    const int* src = ei;
    const int* dst = ei + E;

    // workspace carve (16B-aligned chunks), ~38.4 MB
    char* ws = (char*)d_ws;
    int*            deg     = (int*)ws;            ws += 40064;
    int*            offsets = (int*)ws;            ws += 40064;
    int*            cursor  = (int*)ws;            ws += 40064;
    int*            csr     = (int*)ws;            ws += (size_t)E * 4;
    unsigned short* Ah      = (unsigned short*)ws; ws += (size_t)M * 512 * 2;
    unsigned short* Al      = (unsigned short*)ws; ws += (size_t)M * 512 * 2;
    unsigned short* Bh      = (unsigned short*)ws; ws += (size_t)256 * 512 * 2;
    unsigned short* Bl      = (unsigned short*)ws; ws += (size_t)256 * 512 * 2;
    unsigned short* Wah     = (unsigned short*)ws; ws += (size_t)128 * 256 * 2;
    unsigned short* Wal     = (unsigned short*)ws; ws += (size_t)128 * 256 * 2;
    unsigned short* h1h     = (unsigned short*)ws; ws += (size_t)M * 256 * 2;
    unsigned short* h1l     = (unsigned short*)ws; ws += (size_t)M * 256 * 2;
    float*          h2      = (float*)ws;          ws += (size_t)M * 128 * 4;

    // CSR build
    zero_int<<<(M + 255) / 256, 256, 0, stream>>>(deg, M);
    degree_kernel<<<(E + 255) / 256, 256, 0, stream>>>(dst, deg, E);
    scan_kernel<<<1, 1024, 0, stream>>>(deg, offsets, cursor, M);
    bucket_kernel<<<(E + 255) / 256, 256, 0, stream>>>(src, dst, cursor, csr, E);

    // conversions
    int total4 = M * 64;
    cvt_x_kernel<<<(total4 + 255) / 256, 256, 0, stream>>>(x, Ah, Al, total4);
    cvt_w_kernel<<<(32768 + 255) / 256, 256, 0, stream>>>(W_l, W_r, Bh, Bl);
    cvt_wa_kernel<<<(8192 + 255) / 256, 256, 0, stream>>>(Wa, Wah, Wal);

    // mean aggregation
    agg_kernel<<<(M + 3) / 4, 256, 0, stream>>>(csr, offsets, Ah, Al, M);

    // layer 1: h1 = relu([agg|x] @ [W_l|W_r]^T + b_l) -> bf16 hi/lo
    gemm_mfma<512, 256, true><<<dim3((M + 63) / 64, 4), 256, 0, stream>>>(
        Ah, Al, Bh, Bl, b_l, h1h, h1l, nullptr, M);

    // layer 2: h2 = relu(h1 @ Wa^T + ba) -> fp32
    gemm_mfma<256, 128, false><<<dim3((M + 63) / 64, 2), 256, 0, stream>>>(
        h1h, h1l, Wah, Wal, ba, nullptr, nullptr, h2, M);

    // layers 3..5
    mlp345<<<(M + 31) / 32, 512, 0, stream>>>(h2, W1, b1, W2, b2, W3, b3, out, M);
}

// Round 7
// 216.645 us; speedup vs baseline: 1.9101x; 1.0284x over previous
//
#include <hip/hip_runtime.h>

#define D 256

typedef short short8 __attribute__((ext_vector_type(8)));
typedef float f32x4 __attribute__((ext_vector_type(4)));

// bf16 helpers (RNE)
__device__ __forceinline__ unsigned short f2bf(float f) {
    unsigned int u = __float_as_uint(f);
    unsigned int r = (u + 0x7FFFu + ((u >> 16) & 1u)) >> 16;
    return (unsigned short)r;
}
__device__ __forceinline__ float bf2f(unsigned short h) {
    return __uint_as_float(((unsigned int)h) << 16);
}

// ---------------- fused prep: cvt_x | cvt_w | cvt_wa | degree ----------------
// Block-range split; divergence only at block granularity.
// Ah/Al: [M][512] bf16; cols 0..255 = agg (filled later), 256..511 = x.
// Bh/Bl: [256][512]; row n = [W_l[n] | W_r[n]]. Wah/Wal: Wa 128x256.

__global__ __launch_bounds__(256) void prep_kernel(
    const float* __restrict__ x, const float* __restrict__ W_l,
    const float* __restrict__ W_r, const float* __restrict__ Wa,
    const int* __restrict__ dst,
    unsigned short* __restrict__ Ah, unsigned short* __restrict__ Al,
    unsigned short* __restrict__ Bh, unsigned short* __restrict__ Bl,
    unsigned short* __restrict__ Wah, unsigned short* __restrict__ Wal,
    int* __restrict__ deg, int total4, int E, int bX, int bW, int bWa) {
    const int b = blockIdx.x;
    const int t = threadIdx.x;
    if (b < bX) {
        int i = b * 256 + t;
        if (i >= total4) return;
        int m = i >> 6;
        int c = (i & 63) << 2;
        float4 v = *(const float4*)&x[(long)m * 256 + c];
        ushort4 h, l;
        h.x = f2bf(v.x); l.x = f2bf(v.x - bf2f(h.x));
        h.y = f2bf(v.y); l.y = f2bf(v.y - bf2f(h.y));
        h.z = f2bf(v.z); l.z = f2bf(v.z - bf2f(h.z));
        h.w = f2bf(v.w); l.w = f2bf(v.w - bf2f(h.w));
        *(ushort4*)&Ah[(long)m * 512 + 256 + c] = h;
        *(ushort4*)&Al[(long)m * 512 + 256 + c] = l;
    } else if (b < bW) {
        int i = (b - bX) * 256 + t;   // < 32768
        int n = i >> 7;
        int k4 = (i & 127) << 2;
        float4 v = (k4 < 256) ? *(const float4*)&W_l[(long)n * 256 + k4]
                              : *(const float4*)&W_r[(long)n * 256 + (k4 - 256)];
        ushort4 h, l;
        h.x = f2bf(v.x); l.x = f2bf(v.x - bf2f(h.x));
        h.y = f2bf(v.y); l.y = f2bf(v.y - bf2f(h.y));
        h.z = f2bf(v.z); l.z = f2bf(v.z - bf2f(h.z));
        h.w = f2bf(v.w); l.w = f2bf(v.w - bf2f(h.w));
        *(ushort4*)&Bh[(long)n * 512 + k4] = h;
        *(ushort4*)&Bl[(long)n * 512 + k4] = l;
    } else if (b < bWa) {
        int i = (b - bW) * 256 + t;   // < 8192
        int c = i << 2;
        float4 v = *(const float4*)&Wa[c];
        ushort4 h, l;
        h.x = f2bf(v.x); l.x = f2bf(v.x - bf2f(h.x));
        h.y = f2bf(v.y); l.y = f2bf(v.y - bf2f(h.y));
        h.z = f2bf(v.z); l.z = f2bf(v.z - bf2f(h.z));
        h.w = f2bf(v.w); l.w = f2bf(v.w - bf2f(h.w));
        *(ushort4*)&Wah[c] = h;
        *(ushort4*)&Wal[c] = l;
    } else {
        int e = (b - bWa) * 256 + t;
        if (e < E) atomicAdd(&deg[dst[e]], 1);
    }
}

// ---------------- CSR scan + bucket ----------------

__global__ __launch_bounds__(1024) void scan_kernel(const int* __restrict__ deg,
                                                    int* __restrict__ offsets,
                                                    int* __restrict__ cursor, int n) {
    const int CHUNK = 16;
    __shared__ int s[1024];
    int t = threadIdx.x;
    int base_idx = t * CHUNK;
    int vals[CHUNK];
    int local = 0;
#pragma unroll
    for (int i = 0; i < CHUNK; ++i) {
        int idx = base_idx + i;
        int v = (idx < n) ? deg[idx] : 0;
        vals[i] = v;
        local += v;
    }
    s[t] = local;
    __syncthreads();
    for (int off = 1; off < 1024; off <<= 1) {
        int v = (t >= off) ? s[t - off] : 0;
        __syncthreads();
        s[t] += v;
        __syncthreads();
    }
    int run = s[t] - local;
#pragma unroll
    for (int i = 0; i < CHUNK; ++i) {
        int idx = base_idx + i;
        if (idx < n) {
            offsets[idx] = run;
            cursor[idx]  = run;
            run += vals[i];
        }
    }
    if (t == 1023) offsets[n] = s[1023];
}

__global__ void bucket_kernel(const int* __restrict__ src, const int* __restrict__ dst,
                              int* __restrict__ cursor, int* __restrict__ csr, int E) {
    int e = blockIdx.x * blockDim.x + threadIdx.x;
    if (e < E) {
        int d = dst[e];
        int pos = atomicAdd(&cursor[d], 1);
        csr[pos] = src[e];
    }
}

// ---------------- aggregation: one wave per node, 2 edges in flight ----------------
// Half-wave per edge: 32 lanes x short8 (16B) = full 512B bf16-hi row.
// Halves combined via shfl_down(32) at the end.

__global__ __launch_bounds__(256) void agg_kernel(const int* __restrict__ csr,
                                                  const int* __restrict__ offsets,
                                                  unsigned short* __restrict__ Ah,
                                                  unsigned short* __restrict__ Al, int M) {
    int node = (blockIdx.x * 256 + threadIdx.x) >> 6;
    int lane = threadIdx.x & 63;
    if (node >= M) return;
    int start = offsets[node];
    int end   = offsets[node + 1];
    const int half = lane >> 5;   // 0: even edges, 1: odd edges
    const int hl   = lane & 31;   // 8 cols per lane
    const unsigned short* xb = Ah + 256 + hl * 8;  // row stride 512 shorts
    float acc[8] = {};
    int e = start + half;
    for (; e + 2 < end; e += 4) {   // two pairs in flight
        int s0 = csr[e], s1 = csr[e + 2];
        short8 v0 = *(const short8*)(xb + (long)s0 * 512);
        short8 v1 = *(const short8*)(xb + (long)s1 * 512);
#pragma unroll
        for (int i = 0; i < 8; ++i)
            acc[i] += bf2f((unsigned short)v0[i]) + bf2f((unsigned short)v1[i]);
    }
    for (; e < end; e += 2) {
        int s = csr[e];
        short8 v = *(const short8*)(xb + (long)s * 512);
#pragma unroll
        for (int i = 0; i < 8; ++i) acc[i] += bf2f((unsigned short)v[i]);
    }
#pragma unroll
    for (int i = 0; i < 8; ++i) acc[i] += __shfl_down(acc[i], 32);
    if (half == 0) {
        int cnt = end - start;
        float sc = 1.0f / (float)(cnt > 0 ? cnt : 1);
        short8 h, l;
#pragma unroll
        for (int i = 0; i < 8; ++i) {
            float v = acc[i] * sc;
            unsigned short hh = f2bf(v);
            h[i] = (short)hh;
            l[i] = (short)f2bf(v - bf2f(hh));
        }
        *(short8*)&Ah[(long)node * 512 + hl * 8] = h;
        *(short8*)&Al[(long)node * 512 + hl * 8] = l;
    }
}

// ---------------- unified split-bf16 MFMA GEMM with LDS-staged B ----------------
// C = relu(A @ B^T + bias). Block: 4 waves = 64 rows x 64 cols; B-tile LDS
// double-buffered, shared by the 4 waves. 72-short row stride => 2-way bank
// aliasing only (free, m136). OUT_BF16: store hi/lo planes for next MFMA layer.

template <int K, int NB, bool OUT_BF16>
__global__ __launch_bounds__(256) void gemm_mfma(const unsigned short* __restrict__ Ah,
                                                 const unsigned short* __restrict__ Al,
                                                 const unsigned short* __restrict__ Bh,
                                                 const unsigned short* __restrict__ Bl,
                                                 const float* __restrict__ bias,
                                                 unsigned short* __restrict__ Ch,
                                                 unsigned short* __restrict__ Cl,
                                                 float* __restrict__ Cf, int M) {
    constexpr int NC = K / 64;
    __shared__ __align__(16) unsigned short sBh[2][64][72];
    __shared__ __align__(16) unsigned short sBl[2][64][72];

    const int tid  = threadIdx.x;
    const int wave = tid >> 6;
    const int lane = tid & 63;
    const int l16  = lane & 15;
    const int quad = lane >> 4;
    const int m_base = blockIdx.x * 64 + wave * 16;
    const int n0 = blockIdx.y * 64;

    int rowA = m_base + l16;
    if (rowA > M - 1) rowA = M - 1;  // clamp; stores guarded below
    const unsigned short* pAh = Ah + (long)rowA * K + quad * 8;
    const unsigned short* pAl = Al + (long)rowA * K + quad * 8;

    auto stage = [&](int c) {
        const int buf = c & 1;
        const int kk = c * 64;
#pragma unroll
        for (int i = 0; i < 2; ++i) {
            int idx = tid + i * 256;
            int col = idx >> 3;
            int seg = (idx & 7) * 8;
            *(short8*)&sBh[buf][col][seg] = *(const short8*)&Bh[(long)(n0 + col) * K + kk + seg];
            *(short8*)&sBl[buf][col][seg] = *(const short8*)&Bl[(long)(n0 + col) * K + kk + seg];
        }
    };

    short8 a_h[2][2], a_l[2][2];
    auto loadA = [&](int c) {
        const int buf = c & 1;
#pragma unroll
        for (int ks = 0; ks < 2; ++ks) {
            a_h[buf][ks] = *(const short8*)(pAh + c * 64 + ks * 32);
            a_l[buf][ks] = *(const short8*)(pAl + c * 64 + ks * 32);
        }
    };

    f32x4 acc[4] = {};

    stage(0);
    loadA(0);
    __syncthreads();
#pragma unroll
    for (int c = 0; c < NC; ++c) {
        if (c + 1 < NC) { stage(c + 1); loadA(c + 1); }
        const int buf = c & 1;
#pragma unroll
        for (int ks = 0; ks < 2; ++ks) {
            short8 ah = a_h[buf][ks];
            short8 al = a_l[buf][ks];
#pragma unroll
            for (int t = 0; t < 4; ++t) {
                short8 bh = *(const short8*)&sBh[buf][t * 16 + l16][ks * 32 + quad * 8];
                short8 bl = *(const short8*)&sBl[buf][t * 16 + l16][ks * 32 + quad * 8];
                acc[t] = __builtin_amdgcn_mfma_f32_16x16x32_bf16(ah, bh, acc[t], 0, 0, 0);
                acc[t] = __builtin_amdgcn_mfma_f32_16x16x32_bf16(ah, bl, acc[t], 0, 0, 0);
                acc[t] = __builtin_amdgcn_mfma_f32_16x16x32_bf16(al, bh, acc[t], 0, 0, 0);
            }
        }
        __syncthreads();
    }

    // C/D layout: col = lane&15, row = quad*4 + reg
#pragma unroll
    for (int t = 0; t < 4; ++t) {
        int n = n0 + t * 16 + l16;
        float bv = bias[n];
#pragma unroll
        for (int r = 0; r < 4; ++r) {
            int m = m_base + quad * 4 + r;
            if (m < M) {
                float v = fmaxf(acc[t][r] + bv, 0.f);
                if constexpr (OUT_BF16) {
                    unsigned short h = f2bf(v);
                    Ch[(long)m * NB + n] = h;
                    Cl[(long)m * NB + n] = f2bf(v - bf2f(h));
                } else {
                    Cf[(long)m * NB + n] = v;
                }
            }
        }
    }
}

// ---------------- layers 3..5: 32 rows/block, transposed-LDS weights ----------------

__global__ __launch_bounds__(512) void mlp345(const float* __restrict__ h2,
                                              const float* __restrict__ W1,
                                              const float* __restrict__ b1,
                                              const float* __restrict__ W2,
                                              const float* __restrict__ b2,
                                              const float* __restrict__ W3,
                                              const float* __restrict__ b3,
                                              float* __restrict__ out, int M) {
    __shared__ float sW1T[128][64];
    __shared__ float sW2T[64][32];
    __shared__ float sW3T[32][4];
    __shared__ float sb1[64], sb2[32], sb3[4];
    __shared__ float sH2[32][132];
    __shared__ float sH3[32][68];
    __shared__ float sH4[32][36];

    const int tid = threadIdx.x;
    const int r0 = blockIdx.x * 32;

    for (int i = tid; i < 64 * 128; i += 512) { int o = i >> 7, k = i & 127; sW1T[k][o] = W1[i]; }
    for (int i = tid; i < 32 * 64; i += 512)  { int o = i >> 6, k = i & 63;  sW2T[k][o] = W2[i]; }
    if (tid < 96) { int o = tid >> 5, k = tid & 31; sW3T[k][o] = W3[tid]; }
    if (tid < 64) sb1[tid] = b1[tid];
    else if (tid < 96) sb2[tid - 64] = b2[tid - 64];
    else if (tid < 100) sb3[tid - 96] = b3[tid - 96];

    for (int i = tid; i < 32 * 32; i += 512) {
        int rr = i >> 5;
        int c = (i & 31) << 2;
        float4 v = {0.f, 0.f, 0.f, 0.f};
        if (r0 + rr < M) v = *(const float4*)&h2[(long)(r0 + rr) * 128 + c];
        *(float4*)&sH2[rr][c] = v;
    }
    __syncthreads();

    const int r = tid >> 4;
    const int s = tid & 15;

    {
        float4 acc = *(const float4*)&sb1[s * 4];
        for (int k = 0; k < 128; k += 4) {
            float4 a = *(const float4*)&sH2[r][k];
            float4 w0 = *(const float4*)&sW1T[k + 0][s * 4];
            float4 w1 = *(const float4*)&sW1T[k + 1][s * 4];
            float4 w2 = *(const float4*)&sW1T[k + 2][s * 4];
            float4 w3 = *(const float4*)&sW1T[k + 3][s * 4];
            acc.x = fmaf(a.x, w0.x, fmaf(a.y, w1.x, fmaf(a.z, w2.x, fmaf(a.w, w3.x, acc.x))));
            acc.y = fmaf(a.x, w0.y, fmaf(a.y, w1.y, fmaf(a.z, w2.y, fmaf(a.w, w3.y, acc.y))));
            acc.z = fmaf(a.x, w0.z, fmaf(a.y, w1.z, fmaf(a.z, w2.z, fmaf(a.w, w3.z, acc.z))));
            acc.w = fmaf(a.x, w0.w, fmaf(a.y, w1.w, fmaf(a.z, w2.w, fmaf(a.w, w3.w, acc.w))));
        }
        float4 o;
        o.x = fmaxf(acc.x, 0.f); o.y = fmaxf(acc.y, 0.f);
        o.z = fmaxf(acc.z, 0.f); o.w = fmaxf(acc.w, 0.f);
        *(float4*)&sH3[r][s * 4] = o;
    }
    __syncthreads();

    {
        float a0 = sb2[s * 2], a1 = sb2[s * 2 + 1];
        for (int k = 0; k < 64; k += 4) {
            float4 a = *(const float4*)&sH3[r][k];
            float2 w0 = *(const float2*)&sW2T[k + 0][s * 2];
            float2 w1 = *(const float2*)&sW2T[k + 1][s * 2];
            float2 w2 = *(const float2*)&sW2T[k + 2][s * 2];
            float2 w3 = *(const float2*)&sW2T[k + 3][s * 2];
            a0 = fmaf(a.x, w0.x, fmaf(a.y, w1.x, fmaf(a.z, w2.x, fmaf(a.w, w3.x, a0))));
            a1 = fmaf(a.x, w0.y, fmaf(a.y, w1.y, fmaf(a.z, w2.y, fmaf(a.w, w3.y, a1))));
        }
        float2 o;
        o.x = fmaxf(a0, 0.f);
        o.y = fmaxf(a1, 0.f);
        *(float2*)&sH4[r][s * 2] = o;
    }
    __syncthreads();

    if (s < 3) {
        float acc = sb3[s];
        for (int k = 0; k < 32; k += 4) {
            float4 a = *(const float4*)&sH4[r][k];
            acc = fmaf(a.x, sW3T[k + 0][s],
                  fmaf(a.y, sW3T[k + 1][s],
                  fmaf(a.z, sW3T[k + 2][s],
                  fmaf(a.w, sW3T[k + 3][s], acc))));
        }
        if (r0 + r < M) out[(long)(r0 + r) * 3 + s] = acc;
    }
}

// ---------------- launch ----------------

extern "C" void kernel_launch(void* const* d_in, const int* in_sizes, int n_in,
                              void* d_out, int out_size, void* d_ws, size_t ws_size,
                              hipStream_t stream) {
    const float* x   = (const float*)d_in[0];
    const int*   ei  = (const int*)d_in[1];
    const float* W_l = (const float*)d_in[2];
    const float* b_l = (const float*)d_in[3];
    const float* W_r = (const float*)d_in[4];
    const float* Wa  = (const float*)d_in[5];
    const float* ba  = (const float*)d_in[6];
    const float* W1  = (const float*)d_in[7];
    const float* b1  = (const float*)d_in[8];
    const float* W2  = (const float*)d_in[9];
    const float* b2  = (const float*)d_in[10];
    const float* W3  = (const float*)d_in[11];
    const float* b3  = (const float*)d_in[12];
    float* out = (float*)d_out;

    const int M = in_sizes[0] / D;   // 10000
    const int E = in_sizes[1] / 2;   // 320000
    const int* src = ei;
    const int* dst = ei + E;

    // workspace carve (16B-aligned chunks), ~38.4 MB
    char* ws = (char*)d_ws;
    int*            deg     = (int*)ws;            ws += 40064;
    int*            offsets = (int*)ws;            ws += 40064;
    int*            cursor  = (int*)ws;            ws += 40064;
    int*            csr     = (int*)ws;            ws += (size_t)E * 4;
    unsigned short* Ah      = (unsigned short*)ws; ws += (size_t)M * 512 * 2;
    unsigned short* Al      = (unsigned short*)ws; ws += (size_t)M * 512 * 2;
    unsigned short* Bh      = (unsigned short*)ws; ws += (size_t)256 * 512 * 2;
    unsigned short* Bl      = (unsigned short*)ws; ws += (size_t)256 * 512 * 2;
    unsigned short* Wah     = (unsigned short*)ws; ws += (size_t)128 * 256 * 2;
    unsigned short* Wal     = (unsigned short*)ws; ws += (size_t)128 * 256 * 2;
    unsigned short* h1h     = (unsigned short*)ws; ws += (size_t)M * 256 * 2;
    unsigned short* h1l     = (unsigned short*)ws; ws += (size_t)M * 256 * 2;
    float*          h2      = (float*)ws;          ws += (size_t)M * 128 * 4;

    // zero degree (memset node; capture-safe — harness uses hipMemsetAsync itself)
    hipMemsetAsync(deg, 0, (size_t)M * 4, stream);

    // fused prep: cvt_x | cvt_w | cvt_wa | degree
    const int total4 = M * 64;
    const int bX  = (total4 + 255) / 256;       // 2500
    const int bW  = bX + 128;                   // W_l|W_r: 32768/256
    const int bWa = bW + 32;                    // Wa: 8192/256
    const int grid_prep = bWa + (E + 255) / 256;
    prep_kernel<<<grid_prep, 256, 0, stream>>>(x, W_l, W_r, Wa, dst, Ah, Al, Bh, Bl,
                                               Wah, Wal, deg, total4, E, bX, bW, bWa);

    // CSR scan + bucket
    scan_kernel<<<1, 1024, 0, stream>>>(deg, offsets, cursor, M);
    bucket_kernel<<<(E + 255) / 256, 256, 0, stream>>>(src, dst, cursor, csr, E);

    // mean aggregation
    agg_kernel<<<(M + 3) / 4, 256, 0, stream>>>(csr, offsets, Ah, Al, M);

    // layer 1: h1 = relu([agg|x] @ [W_l|W_r]^T + b_l) -> bf16 hi/lo
    gemm_mfma<512, 256, true><<<dim3((M + 63) / 64, 4), 256, 0, stream>>>(
        Ah, Al, Bh, Bl, b_l, h1h, h1l, nullptr, M);

    // layer 2: h2 = relu(h1 @ Wa^T + ba) -> fp32
    gemm_mfma<256, 128, false><<<dim3((M + 63) / 64, 2), 256, 0, stream>>>(
        h1h, h1l, Wah, Wal, ba, nullptr, nullptr, h2, M);

    // layers 3..5
    mlp345<<<(M + 31) / 32, 512, 0, stream>>>(h2, W1, b1, W2, b2, W3, b3, out, M);
}